// Round 11
// baseline (1316.212 us; speedup 1.0000x reference)
//
#include <hip/hip_runtime.h>
#include <cstdint>

#define S_LEN 32768
#define NV 256
#define NH 512
#define NR 256

typedef short bf16x8 __attribute__((ext_vector_type(8)));
typedef float f32x4 __attribute__((ext_vector_type(4)));
typedef unsigned short ushort_t;

// ---------------- bf16 helpers (bit-level, RTNE) ----------------
__device__ __forceinline__ float b2f(ushort_t u) {
  return __uint_as_float(((uint32_t)u) << 16);
}
__device__ __forceinline__ ushort_t f2b(float f) {
  uint32_t x = __float_as_uint(f);
  uint32_t r = (x + 0x7fffu + ((x >> 16) & 1u)) >> 16;
  return (ushort_t)r;
}

// ---------------- async global->LDS staging ----------------
// R25: R10 regressed both its changes (rnn chunk=64: 143->162us, warmup
// fraction doubled; u8 expansion: ~+5us/dispatch VALU cost > byte savings,
// repeating R0's reg-staging lesson). Revert BOTH to R8's proven config
// (1187us). New single change: pair GEMMs go 256->512 threads per 128x128
// block (8 waves, 2m x 4n, per-wave 64x32, acc[4][2]=32 regs vs 64).
// Same block tile, same K-steps, same staged bytes, same LDS, same traffic
// — only the per-thread reg footprint halves, lifting waves/CU ~12 -> ~24
// (reg-limited 37% -> ~75% cap). NOT R2's mistake (that shrank the BLOCK
// tile and doubled staged bytes).
#define GLOAD_LDS16(gsrc, ldst)                                        \
  __builtin_amdgcn_global_load_lds(                                    \
      (const __attribute__((address_space(1))) void*)(gsrc),           \
      (__attribute__((address_space(3))) void*)(ldst), 16, 0, 0)

// ---------------- host threefry2x32 (key-chain derivation) ----------------
#define TFR(x0,x1,r) { x0 += x1; x1 = ((x1 << (r)) | (x1 >> (32 - (r)))); x1 ^= x0; }
__host__ __forceinline__ void tf2x32(uint32_t k0, uint32_t k1,
                                     uint32_t x0, uint32_t x1,
                                     uint32_t* o0, uint32_t* o1) {
  uint32_t k2 = k0 ^ k1 ^ 0x1BD11BDAu;
  x0 += k0; x1 += k1;
  TFR(x0,x1,13) TFR(x0,x1,15) TFR(x0,x1,26) TFR(x0,x1,6)
  x0 += k1; x1 += k2 + 1u;
  TFR(x0,x1,17) TFR(x0,x1,29) TFR(x0,x1,16) TFR(x0,x1,24)
  x0 += k2; x1 += k0 + 2u;
  TFR(x0,x1,13) TFR(x0,x1,15) TFR(x0,x1,26) TFR(x0,x1,6)
  x0 += k0; x1 += k1 + 3u;
  TFR(x0,x1,17) TFR(x0,x1,29) TFR(x0,x1,16) TFR(x0,x1,24)
  x0 += k1; x1 += k2 + 4u;
  TFR(x0,x1,13) TFR(x0,x1,15) TFR(x0,x1,26) TFR(x0,x1,6)
  x0 += k2; x1 += k0 + 5u;
  *o0 = x0; *o1 = x1;
}

// ---------------- device RNG: murmur3 full-avalanche counter hash ----------------
__device__ __forceinline__ uint32_t fast_hash(uint32_t k0, uint32_t k1, uint32_t idx) {
  uint32_t h = idx ^ k0;
  h *= 0xCC9E2D51u; h = (h << 15) | (h >> 17); h *= 0x1B873593u;
  h ^= k1;
  h ^= h >> 16; h *= 0x85EBCA6Bu;
  h ^= h >> 13; h *= 0xC2B2AE35u;
  h ^= h >> 16;
  return h;
}

__device__ __forceinline__ float wave_reduce(float v) {
#pragma unroll
  for (int o = 32; o > 0; o >>= 1) v += __shfl_down(v, o, 64);
  return v;
}
__device__ __forceinline__ float softplusf(float z) {
  return fmaxf(z, 0.f) + log1pf(expf(-fabsf(z)));
}

// ---------------- epilogue flags ----------------
#define F_SAMP  4    // Bernoulli sample -> C (bf16 0/1)
#define F_H1    8    // sigmoid -> C2 (bf16)
#define F_FE    16   // softplus sum -> fe_acc (acc += -sign*sum)
#define F_MON   32   // monitor sum vs vseqf -> mon_acc

struct GemmArgs {
  const ushort_t* A;    // [M,K] bf16
  const ushort_t* BT;   // [N,K] bf16
  const ushort_t* Ax;   // shifted [M,256] bf16 (bias K-extension, A side)
  const ushort_t* BXT;  // Wycat slice [N,256] bf16 (bias K-ext, B side)
  const float* bvec;    // bveccat slice (f32 per-column bias)
  ushort_t* C;          // sample out [M,N] (bf16 0/1)
  ushort_t* C2;         // sigmoid out (F_H1, bf16)
  const float* vseqf;   // f32 v_seq (F_MON)
  double* fe_acc;
  double* mon_acc;
  float sign;
  uint32_t rk0, rk1;
  int N, K, nbx;        // K = main K (ext adds 256); nbx = N/128
};

// Bijective XCD-chunk swizzle for arbitrary gx (nwg = gx*256, %8==0 always).
// readfirstlane pins results scalar (R6's VGPR lesson).
__device__ __forceinline__ void xcd_swz(int* bx, int* by) {
  const int gx = (int)gridDim.x;
  const int lin = (int)blockIdx.y * gx + (int)blockIdx.x;
  const int cpx = (gx << 8) >> 3;              // gridDim.y == 256 always
  const int w = (lin & 7) * cpx + (lin >> 3);
  const int byv = w / gx;
  *by = __builtin_amdgcn_readfirstlane(byv);
  *bx = __builtin_amdgcn_readfirstlane(w - byv * gx);
}

// ---------------- core GEMM body — 512-thread / 8-wave 128x128 block ----------
// Wave grid 2m x 4n; per-wave 64x32 output -> acc[4][2] (32 regs/thread).
// Same block tile / K-steps / staged bytes / LDS as the 256-thread version;
// only per-thread reg footprint halves -> ~2x waves/CU.
template<int FLAGS>
__device__ __forceinline__ void run_gemm(const GemmArgs& g, int bx, int by,
                                         ushort_t* __restrict__ As,
                                         ushort_t* __restrict__ Bs) {
  const int tid = threadIdx.x;
  const int lane = tid & 63, wave = tid >> 6;      // wave 0..7
  const int wm = wave >> 2, wn = wave & 3;         // 2m x 4n
  const int q = lane >> 4, l16 = lane & 15;
  const int m0 = by * 128, n0 = bx * 128;
  const int N = g.N, K = g.K;
  const int KT = K + 256;            // +bias extension

  f32x4 acc[4][2];
#pragma unroll
  for (int mt = 0; mt < 4; mt++)
#pragma unroll
    for (int nt = 0; nt < 2; nt++) acc[mt][nt] = (f32x4){0.f, 0.f, 0.f, 0.f};

  for (int kk = 0; kk < KT; kk += 64) {
    const ushort_t* Ap; const ushort_t* Bp; size_t lda; int k0;
    if (kk < K) { Ap = g.A;  Bp = g.BT;  lda = (size_t)K; k0 = kk; }
    else        { Ap = g.Ax; Bp = g.BXT; lda = 256;       k0 = kk - K; }
#pragma unroll
    for (int j = 0; j < 2; j++) {
      int c = j * 512 + tid;
      int r = c >> 3, bg = (c & 7) ^ (r & 7);
      const int ldso = (j * 512 + wave * 64) * 8;  // wave-uniform; lane adds *16B
      GLOAD_LDS16(&Ap[(size_t)(m0 + r) * lda + k0 + bg * 8], &As[ldso]);
      GLOAD_LDS16(&Bp[(size_t)(n0 + r) * lda + k0 + bg * 8], &Bs[ldso]);
    }
    __syncthreads();
#pragma unroll
    for (int c = 0; c < 2; c++) {
      bf16x8 af[4], bf[2];
#pragma unroll
      for (int mt = 0; mt < 4; mt++) {
        int r = wm * 64 + mt * 16 + l16;
        af[mt] = *(const bf16x8*)&As[r * 64 + (((c * 4 + q) ^ (r & 7)) * 8)];
      }
#pragma unroll
      for (int nt = 0; nt < 2; nt++) {
        int r = wn * 32 + nt * 16 + l16;
        bf[nt] = *(const bf16x8*)&Bs[r * 64 + (((c * 4 + q) ^ (r & 7)) * 8)];
      }
#pragma unroll
      for (int mt = 0; mt < 4; mt++)
#pragma unroll
        for (int nt = 0; nt < 2; nt++)
          acc[mt][nt] = __builtin_amdgcn_mfma_f32_16x16x32_bf16(
              af[mt], bf[nt], acc[mt][nt], 0, 0, 0);
    }
    __syncthreads();
  }

  float fe_sum = 0.f, mon_sum = 0.f;
#pragma unroll
  for (int mt = 0; mt < 4; mt++) {
#pragma unroll
    for (int nt = 0; nt < 2; nt++) {
      const int gn = n0 + wn * 32 + nt * 16 + l16;
      const int gmb = m0 + wm * 64 + mt * 16 + q * 4;
      const float bvv = g.bvec[gn];
      uint32_t h0 = 0, h1 = 0;
      if constexpr (FLAGS & F_SAMP) {
        uint32_t pb = (uint32_t)((gmb >> 1) * N + gn);
        h0 = fast_hash(g.rk0, g.rk1, pb);               // rows gmb, gmb+1
        h1 = fast_hash(g.rk0, g.rk1, pb + (uint32_t)N); // rows gmb+2, gmb+3
      }
#pragma unroll
      for (int rg = 0; rg < 4; rg++) {
        const int gm = gmb + rg;
        const size_t idx = (size_t)gm * N + gn;
        float z = acc[mt][nt][rg] + bvv;   // matrix bias merged via K-ext
        if constexpr (FLAGS & (F_SAMP | F_H1 | F_MON)) {
          float e = __expf(-z);
          if constexpr (FLAGS & F_SAMP) {
            uint32_t hb = (rg & 2) ? h1 : h0;
            uint32_t ub = (rg & 1) ? (hb >> 16) : (hb & 0xffffu);
            float uu = (float)ub * (1.0f / 65536.0f);
            bool sbit = fmaf(uu, e, uu) < 1.f;  // u < sigmoid(z)
            g.C[idx] = sbit ? (ushort_t)0x3f80 : (ushort_t)0;
          }
          if constexpr (FLAGS & (F_H1 | F_MON)) {
            float pp = __builtin_amdgcn_rcpf(1.f + e);
            if constexpr (FLAGS & F_H1) g.C2[idx] = f2b(pp);
            if constexpr (FLAGS & F_MON) {
              float v = g.vseqf[idx];
              mon_sum += (v != 0.f) ? logf(pp + 1e-10f) : logf(1.f - pp + 1e-10f);
            }
          }
        }
        if constexpr (FLAGS & F_FE) fe_sum += softplusf(z);
      }
    }
  }
  if constexpr (FLAGS & F_FE) {
    float s = wave_reduce(fe_sum);
    if (lane == 0) atomicAdd(g.fe_acc, (double)(-g.sign * s));
  }
  if constexpr (FLAGS & F_MON) {
    float s = wave_reduce(mon_sum);
    if (lane == 0) atomicAdd(g.mon_acc, (double)s);
  }
}

template<int FLAGS>
__global__ __launch_bounds__(512)
void gemm_samp(GemmArgs g) {
  __shared__ ushort_t As[128 * 64];
  __shared__ ushort_t Bs[128 * 64];
  int bx, by;
  xcd_swz(&bx, &by);
  if (bx >= g.nbx) return;
  run_gemm<FLAGS>(g, bx, by, As, Bs);
}

// Flattened pair: gridDim.x = g0.nbx + g1.nbx (no dead blocks, no z dim).
template<int F0, int F1>
__global__ __launch_bounds__(512)
void gemm_pair(GemmArgs g0, GemmArgs g1) {
  __shared__ ushort_t As[128 * 64];
  __shared__ ushort_t Bs[128 * 64];
  int bx, by;
  xcd_swz(&bx, &by);
  if (bx < g0.nbx) {
    run_gemm<F0>(g0, bx, by, As, Bs);
  } else {
    run_gemm<F1>(g1, bx - g0.nbx, by, As, Bs);
  }
}

// ---------------- bias-dot kernel: fe += sum (X1-X2) . (Ash@BXT^T + bvec) ----
// Ash = shifted [S,256], BXT = Wycat slice [N,256], K=256. X1 bf16; X2 f32
// (v_seq) or bf16 (h1 probs). 256-thread (small, off critical path).
template<bool X2F32>
__global__ __launch_bounds__(256)
void dot_bias(const ushort_t* __restrict__ Ash, const ushort_t* __restrict__ BXT,
              const float* __restrict__ bvec, const ushort_t* __restrict__ X1,
              const void* __restrict__ X2, double* __restrict__ fe_acc, int N) {
  __shared__ ushort_t As[128 * 64];
  __shared__ ushort_t Bs[128 * 64];
  const int tid = threadIdx.x;
  const int lane = tid & 63, wave = tid >> 6;
  const int wm = wave >> 1, wn = wave & 1;
  const int q = lane >> 4, l16 = lane & 15;
  int bx, by;
  xcd_swz(&bx, &by);
  const int m0 = by * 128, n0 = bx * 128;

  f32x4 acc[4][4];
#pragma unroll
  for (int i = 0; i < 4; i++)
#pragma unroll
    for (int j = 0; j < 4; j++) acc[i][j] = (f32x4){0.f, 0.f, 0.f, 0.f};

  for (int kk = 0; kk < 256; kk += 64) {
#pragma unroll
    for (int j = 0; j < 4; j++) {
      int c = j * 256 + tid;
      int r = c >> 3, bg = (c & 7) ^ (r & 7);
      const int ldso = (j * 256 + wave * 64) * 8;
      GLOAD_LDS16(&Ash[(size_t)(m0 + r) * 256 + kk + bg * 8], &As[ldso]);
      GLOAD_LDS16(&BXT[(size_t)(n0 + r) * 256 + kk + bg * 8], &Bs[ldso]);
    }
    __syncthreads();
#pragma unroll
    for (int c = 0; c < 2; c++) {
      bf16x8 af[4], bf[4];
#pragma unroll
      for (int mt = 0; mt < 4; mt++) {
        int r = wm * 64 + mt * 16 + l16;
        af[mt] = *(const bf16x8*)&As[r * 64 + (((c * 4 + q) ^ (r & 7)) * 8)];
      }
#pragma unroll
      for (int nt = 0; nt < 4; nt++) {
        int r = wn * 64 + nt * 16 + l16;
        bf[nt] = *(const bf16x8*)&Bs[r * 64 + (((c * 4 + q) ^ (r & 7)) * 8)];
      }
#pragma unroll
      for (int mt = 0; mt < 4; mt++)
#pragma unroll
        for (int nt = 0; nt < 4; nt++)
          acc[mt][nt] = __builtin_amdgcn_mfma_f32_16x16x32_bf16(
              af[mt], bf[nt], acc[mt][nt], 0, 0, 0);
    }
    __syncthreads();
  }

  float fe_sum = 0.f;
#pragma unroll
  for (int mt = 0; mt < 4; mt++)
#pragma unroll
    for (int nt = 0; nt < 4; nt++) {
      const int gn = n0 + wn * 64 + nt * 16 + l16;
      const int gmb = m0 + wm * 64 + mt * 16 + q * 4;
      const float bvv = bvec[gn];
#pragma unroll
      for (int rg = 0; rg < 4; rg++) {
        const size_t idx = (size_t)(gmb + rg) * N + gn;
        float be = acc[mt][nt][rg] + bvv;
        float x1 = b2f(X1[idx]);
        float x2 = X2F32 ? ((const float*)X2)[idx]
                         : b2f(((const ushort_t*)X2)[idx]);
        fe_sum += be * (x1 - x2);
      }
    }
  float s = wave_reduce(fe_sum);
  if (lane == 0) atomicAdd(fe_acc, (double)s);
}

// ---------------- plain GEMM + f32-vector bias (Arnn pre-activation) ------------
__global__ __launch_bounds__(256)
void gemm_bias(const ushort_t* __restrict__ A, const ushort_t* __restrict__ BT,
               const float* __restrict__ biasv, float* __restrict__ Cf,
               int M, int N, int K) {
  __shared__ ushort_t As[128 * 64];
  __shared__ ushort_t Bs[128 * 64];
  const int tid = threadIdx.x;
  const int lane = tid & 63, wave = tid >> 6;
  const int wm = wave >> 1, wn = wave & 1;
  const int q = lane >> 4, l16 = lane & 15;
  int bx, by;
  xcd_swz(&bx, &by);
  const int m0 = by * 128, n0 = bx * 128;
  (void)lane;

  f32x4 acc[4][4];
#pragma unroll
  for (int i = 0; i < 4; i++)
#pragma unroll
    for (int j = 0; j < 4; j++) acc[i][j] = (f32x4){0.f, 0.f, 0.f, 0.f};

  for (int kk = 0; kk < K; kk += 64) {
#pragma unroll
    for (int j = 0; j < 4; j++) {
      int c = j * 256 + tid;
      int r = c >> 3, bg = (c & 7) ^ (r & 7);
      const int ldso = (j * 256 + wave * 64) * 8;
      GLOAD_LDS16(&A[(size_t)(m0 + r) * K + kk + bg * 8], &As[ldso]);
      GLOAD_LDS16(&BT[(size_t)(n0 + r) * K + kk + bg * 8], &Bs[ldso]);
    }
    __syncthreads();
#pragma unroll
    for (int c = 0; c < 2; c++) {
      bf16x8 af[4], bf[4];
#pragma unroll
      for (int mt = 0; mt < 4; mt++) {
        int r = wm * 64 + mt * 16 + l16;
        af[mt] = *(const bf16x8*)&As[r * 64 + (((c * 4 + q) ^ (r & 7)) * 8)];
      }
#pragma unroll
      for (int nt = 0; nt < 4; nt++) {
        int r = wn * 64 + nt * 16 + l16;
        bf[nt] = *(const bf16x8*)&Bs[r * 64 + (((c * 4 + q) ^ (r & 7)) * 8)];
      }
#pragma unroll
      for (int mt = 0; mt < 4; mt++)
#pragma unroll
        for (int nt = 0; nt < 4; nt++)
          acc[mt][nt] = __builtin_amdgcn_mfma_f32_16x16x32_bf16(
              af[mt], bf[nt], acc[mt][nt], 0, 0, 0);
    }
    __syncthreads();
  }

#pragma unroll
  for (int mt = 0; mt < 4; mt++)
#pragma unroll
    for (int nt = 0; nt < 4; nt++) {
      const int gn = n0 + wn * 64 + nt * 16 + l16;
      const int gmb = m0 + wm * 64 + mt * 16 + q * 4;
      const float bvv = biasv[gn];
#pragma unroll
      for (int rg = 0; rg < 4; rg++)
        Cf[(size_t)(gmb + rg) * N + gn] = acc[mt][nt][rg] + bvv;
    }
}

// ---------------- chunked RNN scan v5 (R8-proven: 256 blocks x 128 steps) -----
__global__ __launch_bounds__(1024, 1)
void rnn_scan(const float* __restrict__ Apre, const float* __restrict__ Wuu,
              ushort_t* __restrict__ shifted) {
  const int tid = threadIdx.x;
  const int j = tid >> 2;
  const int s = tid & 3;
  const int t_begin = blockIdx.x * 128;
  const int t_end = t_begin + 128;
  const int t0 = (t_begin >= 16) ? (t_begin - 16) : 0;

  float w[64];
#pragma unroll
  for (int i = 0; i < 64; i++) w[i] = Wuu[(size_t)(s * 64 + i) * 256 + j];

  __shared__ float u[2][280];
  __shared__ float asg[32 * 256];
  if (tid < 256) u[0][(tid >> 6) * 68 + (tid & 63)] = 0.f;
  if (blockIdx.x == 0 && s == 0) shifted[j] = 0;
  __syncthreads();

  const int jp = (j >> 6) * 68 + (j & 63);
  int p = 0;
  for (int tb = t0; tb < t_end; tb += 32) {
    int srow = tb + (tid >> 5);
    if (srow >= S_LEN) srow = S_LEN - 1;
    int scol = (tid & 31) * 8;
    float4 a0 = *(const float4*)&Apre[(size_t)srow * 256 + scol];
    float4 a1 = *(const float4*)&Apre[(size_t)srow * 256 + scol + 4];
    *(float4*)&asg[(tid >> 5) * 256 + scol] = a0;
    *(float4*)&asg[(tid >> 5) * 256 + scol + 4] = a1;
    __syncthreads();
#pragma unroll 1
    for (int i = 0; i < 32; i++) {
      const int t = tb + i;
      if (t >= t_end) break;
      float p0 = 0.f, p1 = 0.f, p2 = 0.f, p3 = 0.f;
#pragma unroll
      for (int qq = 0; qq < 64; qq += 4) {
        float4 uv = *(const float4*)&u[p][s * 68 + qq];
        p0 = fmaf(uv.x, w[qq + 0], p0);
        p1 = fmaf(uv.y, w[qq + 1], p1);
        p2 = fmaf(uv.z, w[qq + 2], p2);
        p3 = fmaf(uv.w, w[qq + 3], p3);
      }
      float ps = (p0 + p1) + (p2 + p3);
      ps += __shfl_xor(ps, 1, 64);
      ps += __shfl_xor(ps, 2, 64);
      float z = asg[i * 256 + j] + ps;
      float e = __expf(2.f * z);
      float unew = 1.f - 2.f * __builtin_amdgcn_rcpf(e + 1.f);
      if (s == 0) {
        u[1 - p][jp] = unew;
        if (t >= t_begin && (t + 1) < S_LEN)
          shifted[(size_t)(t + 1) * 256 + j] = f2b(unew);
      }
      __syncthreads();
      p ^= 1;
    }
  }
}

// ---------------- single prep kernel ----------------
__global__ __launch_bounds__(256)
void prep_all(const float* __restrict__ v_seq, ushort_t* __restrict__ vseq_bf,
              const float* __restrict__ Wyv, const float* __restrict__ Wyh1,
              const float* __restrict__ Wyh2, ushort_t* __restrict__ Wycat,
              const float* __restrict__ W1, ushort_t* __restrict__ BTw1t,
              ushort_t* __restrict__ BTw1,
              const float* __restrict__ W2, ushort_t* __restrict__ BTw2t,
              ushort_t* __restrict__ BTw2,
              const float* __restrict__ Wvu, ushort_t* __restrict__ BTwvu,
              const float* __restrict__ bv, const float* __restrict__ bh1,
              const float* __restrict__ bh2, float* __restrict__ bveccat) {
  int b = blockIdx.x;
  const int tid = threadIdx.x;
  if (b < 32768) { int i = b * 256 + tid; vseq_bf[i] = f2b(v_seq[i]); return; }
  b -= 32768;
  if (b < 256)  { int i = b * 256 + tid; Wycat[i] = f2b(Wyv[i]); return; }
  b -= 256;
  if (b < 512)  { int i = b * 256 + tid; Wycat[65536 + i] = f2b(Wyh1[i]); return; }
  b -= 512;
  if (b < 512)  { int i = b * 256 + tid; Wycat[196608 + i] = f2b(Wyh2[i]); return; }
  b -= 512;
  if (b < 512)  { int i = b * 256 + tid; BTw1t[i] = f2b(W1[i]); return; }
  b -= 512;
  if (b < 1024) { int i = b * 256 + tid; BTw2t[i] = f2b(W2[i]); return; }
  b -= 1024;
  if (b < 256)  { int i = b * 256 + tid; int r = i >> 8, c = i & 255;
                  BTwvu[c * 256 + r] = f2b(Wvu[i]); return; }
  b -= 256;
  if (b < 512)  { int i = b * 256 + tid; int r = i >> 9, c = i & 511;
                  BTw1[(size_t)c * 256 + r] = f2b(W1[i]); return; }
  b -= 512;
  if (b < 1024) { int i = b * 256 + tid; int r = i >> 9, c = i & 511;
                  BTw2[(size_t)c * 512 + r] = f2b(W2[i]); return; }
  b -= 1024;
  { int i = b * 256 + tid;
    if (i < 1280)
      bveccat[i] = (i < 256) ? bv[i] : (i < 768) ? bh1[i - 256] : bh2[i - 768]; }
}

__global__ void finalize_kernel(const double* __restrict__ acc, float* __restrict__ out) {
  out[0] = (float)(acc[0] / (double)S_LEN);
  out[1] = (float)(acc[1] / (double)S_LEN);
}

// ---------------- host orchestration ----------------
extern "C" void kernel_launch(void* const* d_in, const int* in_sizes, int n_in,
                              void* d_out, int out_size, void* d_ws, size_t ws_size,
                              hipStream_t stream) {
  (void)in_sizes; (void)n_in; (void)out_size; (void)ws_size;
  const float* v_seq = (const float*)d_in[0];
  const float* W1    = (const float*)d_in[1];
  const float* bv    = (const float*)d_in[2];
  const float* bh1   = (const float*)d_in[3];
  const float* W2    = (const float*)d_in[4];
  const float* bh2   = (const float*)d_in[5];
  const float* Wyv   = (const float*)d_in[6];
  const float* Wyh1  = (const float*)d_in[7];
  const float* Wyh2  = (const float*)d_in[8];
  const float* Wvu   = (const float*)d_in[9];
  const float* Wuu   = (const float*)d_in[10];
  const float* bu    = (const float*)d_in[11];
  float* out = (float*)d_out;

  const size_t SN = (size_t)S_LEN * NV;   // 8.4M
  const size_t SH = (size_t)S_LEN * NH;   // 16.8M
  char* base = (char*)d_ws;
  size_t cur = 0;
  auto take = [&](size_t bytes) { size_t o = cur; cur += (bytes + 255) & ~(size_t)255; return o; };
  double*   acc      = (double*)  (base + take(64));
  ushort_t* BTwvu    = (ushort_t*)(base + take(65536 * 2));
  ushort_t* Wycat    = (ushort_t*)(base + take((size_t)1280 * NR * 2));
  float*    bveccat  = (float*)   (base + take(1280 * 4));
  ushort_t* BTw1     = (ushort_t*)(base + take(131072 * 2));   // W1^T [512,256]
  ushort_t* BTw1t    = (ushort_t*)(base + take(131072 * 2));   // W1   [256,512]
  ushort_t* BTw2     = (ushort_t*)(base + take(262144 * 2));   // W2^T [512,512]
  ushort_t* BTw2t    = (ushort_t*)(base + take(262144 * 2));   // W2   [512,512]
  ushort_t* vseq_bf  = (ushort_t*)(base + take(SN * 2));
  ushort_t* shifted  = (ushort_t*)(base + take(SN * 2));
  float*    Arnn     = (float*)   (base + take(SN * 4));       // RNN pre-activation
  ushort_t* h1buf    = (ushort_t*)(base + take(SH * 2));       // h1 probs bf16
  ushort_t* sampA    = (ushort_t*)(base + take(SH * 2));       // RBM1 h samples
  ushort_t* sampB    = (ushort_t*)(base + take(SN * 2));       // RBM1 v samples
  ushort_t* sampC    = (ushort_t*)(base + take(SH * 2));       // RBM2 h2 samples
  ushort_t* sampD    = (ushort_t*)(base + take(SH * 2));       // RBM2 h1 samples

  uint32_t ka[20], kb[20];
  uint32_t K0 = 0u, K1 = 42u;
  for (int it = 0; it < 10; it++) {
    uint32_t n0, n1, a0, a1, b0, b1;
    tf2x32(K0, K1, 0u, 0u, &n0, &n1);
    tf2x32(K0, K1, 0u, 1u, &a0, &a1);
    tf2x32(K0, K1, 0u, 2u, &b0, &b1);
    ka[2 * it] = a0; kb[2 * it] = a1;
    ka[2 * it + 1] = b0; kb[2 * it + 1] = b1;
    K0 = n0; K1 = n1;
  }

  hipMemsetAsync(acc, 0, 2 * sizeof(double), stream);

  dim3 blk(256);
  dim3 blk512(512);
  prep_all<<<dim3(37381), blk, 0, stream>>>(
      v_seq, vseq_bf, Wyv, Wyh1, Wyh2, Wycat, W1, BTw1t, BTw1,
      W2, BTw2t, BTw2, Wvu, BTwvu, bv, bh1, bh2, bveccat);

  const int M = S_LEN;
  gemm_bias<<<dim3(2, M / 128), blk, 0, stream>>>(
      vseq_bf, BTwvu, bu, Arnn, M, NV, NV);
  rnn_scan<<<dim3(S_LEN / 128), dim3(1024), 0, stream>>>(Arnn, Wuu, shifted);

  const int OFF_BV = 0, OFF_BH1 = NV, OFF_BH2 = NV + NH;
  auto mk = [&](const ushort_t* A, const ushort_t* BT, int boff, ushort_t* C,
                ushort_t* C2, const float* vs, float sign, int key, int N, int K) {
    GemmArgs g;
    g.A = A; g.BT = BT;
    g.Ax = shifted;
    g.BXT = Wycat + (size_t)boff * 256;
    g.bvec = bveccat + boff;
    g.C = C; g.C2 = C2; g.vseqf = vs;
    g.fe_acc = acc; g.mon_acc = acc + 1; g.sign = sign;
    g.rk0 = key >= 0 ? ka[key] : 0; g.rk1 = key >= 0 ? kb[key] : 0;
    g.N = N; g.K = K; g.nbx = N / 128;
    return g;
  };

  // G1: sample h (sampA), h1 probs (h1buf), cost1 -= softplus(v_seq@W1+bh1t)
  gemm_samp<F_SAMP | F_H1 | F_FE>
      <<<dim3(4, M / 128), blk512, 0, stream>>>(
      mk(vseq_bf, BTw1, OFF_BH1, sampA, h1buf, nullptr, 1.0f, 0, NH, NV));

  // 10 flattened pair dispatches: RBM1 chain + RBM2 chain
  GemmArgs V[5], Hh[4], A2g[5], B2g[5];
  for (int it = 0; it < 5; it++) {
    if (it > 0)
      Hh[it - 1] = mk(sampB, BTw1, OFF_BH1, sampA, nullptr, nullptr, 0.f,
                      2 * it, NH, NV);
    V[it] = mk(sampA, BTw1t, OFF_BV, sampB, nullptr,
               (it == 4) ? v_seq : nullptr, 0.f, 2 * it + 1, NV, NH);
    A2g[it] = mk((it == 0) ? h1buf : sampD,
                 BTw2, OFF_BH2, sampC, nullptr, nullptr,
                 (it == 0) ? 1.0f : 0.f, 10 + 2 * it, NH, NH);
    B2g[it] = mk(sampC, BTw2t, OFF_BH1, sampD, nullptr, nullptr, 0.f,
                 11 + 2 * it, NH, NH);
  }
  GemmArgs FE1 = mk(sampB, BTw1, OFF_BH1, nullptr, nullptr, nullptr, -1.0f,
                    -1, NH, NV);
  GemmArgs FE2 = mk(sampD, BTw2, OFF_BH2, nullptr, nullptr, nullptr, -1.0f,
                    -1, NH, NH);

  auto pgrid = [&](const GemmArgs& a, const GemmArgs& b) {
    return dim3(a.nbx + b.nbx, M / 128);
  };

  gemm_pair<F_SAMP, F_SAMP | F_FE>
      <<<pgrid(V[0], A2g[0]), blk512, 0, stream>>>(V[0], A2g[0]);  // A2g[0]: h1buf
  gemm_pair<F_SAMP, F_SAMP>
      <<<pgrid(Hh[0], B2g[0]), blk512, 0, stream>>>(Hh[0], B2g[0]);
  gemm_pair<F_SAMP, F_SAMP>
      <<<pgrid(V[1], A2g[1]), blk512, 0, stream>>>(V[1], A2g[1]);
  gemm_pair<F_SAMP, F_SAMP>
      <<<pgrid(Hh[1], B2g[1]), blk512, 0, stream>>>(Hh[1], B2g[1]);
  gemm_pair<F_SAMP, F_SAMP>
      <<<pgrid(V[2], A2g[2]), blk512, 0, stream>>>(V[2], A2g[2]);
  gemm_pair<F_SAMP, F_SAMP>
      <<<pgrid(Hh[2], B2g[2]), blk512, 0, stream>>>(Hh[2], B2g[2]);
  gemm_pair<F_SAMP, F_SAMP>
      <<<pgrid(V[3], A2g[3]), blk512, 0, stream>>>(V[3], A2g[3]);
  gemm_pair<F_SAMP, F_SAMP>
      <<<pgrid(Hh[3], B2g[3]), blk512, 0, stream>>>(Hh[3], B2g[3]);
  gemm_pair<F_SAMP | F_MON, F_SAMP>
      <<<pgrid(V[4], A2g[4]), blk512, 0, stream>>>(V[4], A2g[4]);
  gemm_pair<F_FE, F_SAMP>
      <<<pgrid(FE1, B2g[4]), blk512, 0, stream>>>(FE1, B2g[4]);

  // FE2(sample): cost2 += softplus(h1s@W2 + bh2t)
  gemm_samp<F_FE><<<dim3(4, M / 128), blk512, 0, stream>>>(FE2);

  // Bias-dot terms (outside the hot GEMMs):
  // cost1 += sum (v_samp_final - v_seq) . bv_t      [X1=sampB, X2=v_seq f32]
  dot_bias<true><<<dim3(2, M / 128), blk, 0, stream>>>(
      shifted, Wycat + (size_t)OFF_BV * 256, bveccat + OFF_BV,
      sampB, v_seq, acc, NV);
  // cost2 += sum (h1_samp_final - h1) . bh1t        [X1=sampD, X2=h1buf bf16]
  dot_bias<false><<<dim3(4, M / 128), blk, 0, stream>>>(
      shifted, Wycat + (size_t)OFF_BH1 * 256, bveccat + OFF_BH1,
      sampD, h1buf, acc, NH);

  finalize_kernel<<<1, 1, 0, stream>>>(acc, out);
}

// Round 12
// 1184.029 us; speedup vs baseline: 1.1116x; 1.1116x over previous
//
#include <hip/hip_runtime.h>
#include <cstdint>

#define S_LEN 32768
#define NV 256
#define NH 512
#define NR 256

typedef short bf16x8 __attribute__((ext_vector_type(8)));
typedef float f32x4 __attribute__((ext_vector_type(4)));
typedef unsigned short ushort_t;

// ---------------- bf16 helpers (bit-level, RTNE) ----------------
__device__ __forceinline__ float b2f(ushort_t u) {
  return __uint_as_float(((uint32_t)u) << 16);
}
__device__ __forceinline__ ushort_t f2b(float f) {
  uint32_t x = __float_as_uint(f);
  uint32_t r = (x + 0x7fffu + ((x >> 16) & 1u)) >> 16;
  return (ushort_t)r;
}

// ---------------- async global->LDS staging ----------------
// R26: revert to the R8 configuration verbatim (best verified: 1187us).
// The R9-R11 probes all regressed and bracketed R8 from every direction:
//  - occupancy is NOT the lever: R11 (512t, occ 20->46%) dropped effective
//    BW 1.4->0.69 TB/s; R2/R7 (other direction) also worse. The pair GEMMs
//    are barrier-drain-structured; R8's 256t/4-wave split is the sweet spot.
//  - byte-cutting via u8 reg-staging costs more VALU than it saves (R10),
//    repeating R0's lesson; gload_lds + bf16 samples is optimal.
//  - rnn chunk=128 (+16 warmup) beats chunk=64 (warmup fraction doubles).
// Config: 128x128 tile / 256 threads / single-buffer 32KB LDS / merged-acc
// bias-K-extension / standalone dot_bias kernels / bijective XCD swizzle.
#define GLOAD_LDS16(gsrc, ldst)                                        \
  __builtin_amdgcn_global_load_lds(                                    \
      (const __attribute__((address_space(1))) void*)(gsrc),           \
      (__attribute__((address_space(3))) void*)(ldst), 16, 0, 0)

// ---------------- host threefry2x32 (key-chain derivation) ----------------
#define TFR(x0,x1,r) { x0 += x1; x1 = ((x1 << (r)) | (x1 >> (32 - (r)))); x1 ^= x0; }
__host__ __forceinline__ void tf2x32(uint32_t k0, uint32_t k1,
                                     uint32_t x0, uint32_t x1,
                                     uint32_t* o0, uint32_t* o1) {
  uint32_t k2 = k0 ^ k1 ^ 0x1BD11BDAu;
  x0 += k0; x1 += k1;
  TFR(x0,x1,13) TFR(x0,x1,15) TFR(x0,x1,26) TFR(x0,x1,6)
  x0 += k1; x1 += k2 + 1u;
  TFR(x0,x1,17) TFR(x0,x1,29) TFR(x0,x1,16) TFR(x0,x1,24)
  x0 += k2; x1 += k0 + 2u;
  TFR(x0,x1,13) TFR(x0,x1,15) TFR(x0,x1,26) TFR(x0,x1,6)
  x0 += k0; x1 += k1 + 3u;
  TFR(x0,x1,17) TFR(x0,x1,29) TFR(x0,x1,16) TFR(x0,x1,24)
  x0 += k1; x1 += k2 + 4u;
  TFR(x0,x1,13) TFR(x0,x1,15) TFR(x0,x1,26) TFR(x0,x1,6)
  x0 += k2; x1 += k0 + 5u;
  *o0 = x0; *o1 = x1;
}

// ---------------- device RNG: murmur3 full-avalanche counter hash ----------------
__device__ __forceinline__ uint32_t fast_hash(uint32_t k0, uint32_t k1, uint32_t idx) {
  uint32_t h = idx ^ k0;
  h *= 0xCC9E2D51u; h = (h << 15) | (h >> 17); h *= 0x1B873593u;
  h ^= k1;
  h ^= h >> 16; h *= 0x85EBCA6Bu;
  h ^= h >> 13; h *= 0xC2B2AE35u;
  h ^= h >> 16;
  return h;
}

__device__ __forceinline__ float wave_reduce(float v) {
#pragma unroll
  for (int o = 32; o > 0; o >>= 1) v += __shfl_down(v, o, 64);
  return v;
}
__device__ __forceinline__ float softplusf(float z) {
  return fmaxf(z, 0.f) + log1pf(expf(-fabsf(z)));
}

// ---------------- epilogue flags ----------------
#define F_SAMP  4    // Bernoulli sample -> C (bf16 0/1)
#define F_H1    8    // sigmoid -> C2 (bf16)
#define F_FE    16   // softplus sum -> fe_acc (acc += -sign*sum)
#define F_MON   32   // monitor sum vs vseqf -> mon_acc

struct GemmArgs {
  const ushort_t* A;    // [M,K] bf16
  const ushort_t* BT;   // [N,K] bf16
  const ushort_t* Ax;   // shifted [M,256] bf16 (bias K-extension, A side)
  const ushort_t* BXT;  // Wycat slice [N,256] bf16 (bias K-ext, B side)
  const float* bvec;    // bveccat slice (f32 per-column bias)
  ushort_t* C;          // sample out [M,N] (bf16 0/1)
  ushort_t* C2;         // sigmoid out (F_H1, bf16)
  const float* vseqf;   // f32 v_seq (F_MON)
  double* fe_acc;
  double* mon_acc;
  float sign;
  uint32_t rk0, rk1;
  int N, K, nbx;        // K = main K (ext adds 256); nbx = N/128
};

// Bijective XCD-chunk swizzle for arbitrary gx (nwg = gx*256, %8==0 always).
// readfirstlane pins results scalar (R6's VGPR lesson).
__device__ __forceinline__ void xcd_swz(int* bx, int* by) {
  const int gx = (int)gridDim.x;
  const int lin = (int)blockIdx.y * gx + (int)blockIdx.x;
  const int cpx = (gx << 8) >> 3;              // gridDim.y == 256 always
  const int w = (lin & 7) * cpx + (lin >> 3);
  const int byv = w / gx;
  *by = __builtin_amdgcn_readfirstlane(byv);
  *bx = __builtin_amdgcn_readfirstlane(w - byv * gx);
}

// ---------------- core GEMM body — merged-acc fused-bias-K, single-buffer ----
template<int FLAGS>
__device__ __forceinline__ void run_gemm(const GemmArgs& g, int bx, int by,
                                         ushort_t* __restrict__ As,
                                         ushort_t* __restrict__ Bs) {
  const int tid = threadIdx.x;
  const int lane = tid & 63, wave = tid >> 6;
  const int wm = wave >> 1, wn = wave & 1;
  const int q = lane >> 4, l16 = lane & 15;
  const int m0 = by * 128, n0 = bx * 128;
  const int N = g.N, K = g.K;
  const int KT = K + 256;            // +bias extension

  f32x4 acc[4][4];
#pragma unroll
  for (int mt = 0; mt < 4; mt++)
#pragma unroll
    for (int nt = 0; nt < 4; nt++) acc[mt][nt] = (f32x4){0.f, 0.f, 0.f, 0.f};

  for (int kk = 0; kk < KT; kk += 64) {
    const ushort_t* Ap; const ushort_t* Bp; size_t lda; int k0;
    if (kk < K) { Ap = g.A;  Bp = g.BT;  lda = (size_t)K; k0 = kk; }
    else        { Ap = g.Ax; Bp = g.BXT; lda = 256;       k0 = kk - K; }
#pragma unroll
    for (int j = 0; j < 4; j++) {
      int c = j * 256 + tid;
      int r = c >> 3, bg = (c & 7) ^ (r & 7);
      const int ldso = (j * 256 + wave * 64) * 8;  // wave-uniform; lane adds *16B
      GLOAD_LDS16(&Ap[(size_t)(m0 + r) * lda + k0 + bg * 8], &As[ldso]);
      GLOAD_LDS16(&Bp[(size_t)(n0 + r) * lda + k0 + bg * 8], &Bs[ldso]);
    }
    __syncthreads();
#pragma unroll
    for (int c = 0; c < 2; c++) {
      bf16x8 af[4], bf[4];
#pragma unroll
      for (int mt = 0; mt < 4; mt++) {
        int r = wm * 64 + mt * 16 + l16;
        af[mt] = *(const bf16x8*)&As[r * 64 + (((c * 4 + q) ^ (r & 7)) * 8)];
      }
#pragma unroll
      for (int nt = 0; nt < 4; nt++) {
        int r = wn * 64 + nt * 16 + l16;
        bf[nt] = *(const bf16x8*)&Bs[r * 64 + (((c * 4 + q) ^ (r & 7)) * 8)];
      }
#pragma unroll
      for (int mt = 0; mt < 4; mt++)
#pragma unroll
        for (int nt = 0; nt < 4; nt++)
          acc[mt][nt] = __builtin_amdgcn_mfma_f32_16x16x32_bf16(
              af[mt], bf[nt], acc[mt][nt], 0, 0, 0);
    }
    __syncthreads();
  }

  float fe_sum = 0.f, mon_sum = 0.f;
#pragma unroll
  for (int mt = 0; mt < 4; mt++) {
#pragma unroll
    for (int nt = 0; nt < 4; nt++) {
      const int gn = n0 + wn * 64 + nt * 16 + l16;
      const int gmb = m0 + wm * 64 + mt * 16 + q * 4;
      const float bvv = g.bvec[gn];
      uint32_t h0 = 0, h1 = 0;
      if constexpr (FLAGS & F_SAMP) {
        uint32_t pb = (uint32_t)((gmb >> 1) * N + gn);
        h0 = fast_hash(g.rk0, g.rk1, pb);               // rows gmb, gmb+1
        h1 = fast_hash(g.rk0, g.rk1, pb + (uint32_t)N); // rows gmb+2, gmb+3
      }
#pragma unroll
      for (int rg = 0; rg < 4; rg++) {
        const int gm = gmb + rg;
        const size_t idx = (size_t)gm * N + gn;
        float z = acc[mt][nt][rg] + bvv;   // matrix bias merged via K-ext
        if constexpr (FLAGS & (F_SAMP | F_H1 | F_MON)) {
          float e = __expf(-z);
          if constexpr (FLAGS & F_SAMP) {
            uint32_t hb = (rg & 2) ? h1 : h0;
            uint32_t ub = (rg & 1) ? (hb >> 16) : (hb & 0xffffu);
            float uu = (float)ub * (1.0f / 65536.0f);
            bool sbit = fmaf(uu, e, uu) < 1.f;  // u < sigmoid(z)
            g.C[idx] = sbit ? (ushort_t)0x3f80 : (ushort_t)0;
          }
          if constexpr (FLAGS & (F_H1 | F_MON)) {
            float pp = __builtin_amdgcn_rcpf(1.f + e);
            if constexpr (FLAGS & F_H1) g.C2[idx] = f2b(pp);
            if constexpr (FLAGS & F_MON) {
              float v = g.vseqf[idx];
              mon_sum += (v != 0.f) ? logf(pp + 1e-10f) : logf(1.f - pp + 1e-10f);
            }
          }
        }
        if constexpr (FLAGS & F_FE) fe_sum += softplusf(z);
      }
    }
  }
  if constexpr (FLAGS & F_FE) {
    float s = wave_reduce(fe_sum);
    if (lane == 0) atomicAdd(g.fe_acc, (double)(-g.sign * s));
  }
  if constexpr (FLAGS & F_MON) {
    float s = wave_reduce(mon_sum);
    if (lane == 0) atomicAdd(g.mon_acc, (double)s);
  }
}

template<int FLAGS>
__global__ __launch_bounds__(256)
void gemm_samp(GemmArgs g) {
  __shared__ ushort_t As[128 * 64];
  __shared__ ushort_t Bs[128 * 64];
  int bx, by;
  xcd_swz(&bx, &by);
  if (bx >= g.nbx) return;
  run_gemm<FLAGS>(g, bx, by, As, Bs);
}

// Flattened pair: gridDim.x = g0.nbx + g1.nbx (no dead blocks, no z dim).
template<int F0, int F1>
__global__ __launch_bounds__(256)
void gemm_pair(GemmArgs g0, GemmArgs g1) {
  __shared__ ushort_t As[128 * 64];
  __shared__ ushort_t Bs[128 * 64];
  int bx, by;
  xcd_swz(&bx, &by);
  if (bx < g0.nbx) {
    run_gemm<F0>(g0, bx, by, As, Bs);
  } else {
    run_gemm<F1>(g1, bx - g0.nbx, by, As, Bs);
  }
}

// ---------------- bias-dot kernel: fe += sum (X1-X2) . (Ash@BXT^T + bvec) ----
// Ash = shifted [S,256], BXT = Wycat slice [N,256], K=256. X1 bf16; X2 f32
// (v_seq) or bf16 (h1 probs).
template<bool X2F32>
__global__ __launch_bounds__(256)
void dot_bias(const ushort_t* __restrict__ Ash, const ushort_t* __restrict__ BXT,
              const float* __restrict__ bvec, const ushort_t* __restrict__ X1,
              const void* __restrict__ X2, double* __restrict__ fe_acc, int N) {
  __shared__ ushort_t As[128 * 64];
  __shared__ ushort_t Bs[128 * 64];
  const int tid = threadIdx.x;
  const int lane = tid & 63, wave = tid >> 6;
  const int wm = wave >> 1, wn = wave & 1;
  const int q = lane >> 4, l16 = lane & 15;
  int bx, by;
  xcd_swz(&bx, &by);
  const int m0 = by * 128, n0 = bx * 128;

  f32x4 acc[4][4];
#pragma unroll
  for (int i = 0; i < 4; i++)
#pragma unroll
    for (int j = 0; j < 4; j++) acc[i][j] = (f32x4){0.f, 0.f, 0.f, 0.f};

  for (int kk = 0; kk < 256; kk += 64) {
#pragma unroll
    for (int j = 0; j < 4; j++) {
      int c = j * 256 + tid;
      int r = c >> 3, bg = (c & 7) ^ (r & 7);
      const int ldso = (j * 256 + wave * 64) * 8;
      GLOAD_LDS16(&Ash[(size_t)(m0 + r) * 256 + kk + bg * 8], &As[ldso]);
      GLOAD_LDS16(&BXT[(size_t)(n0 + r) * 256 + kk + bg * 8], &Bs[ldso]);
    }
    __syncthreads();
#pragma unroll
    for (int c = 0; c < 2; c++) {
      bf16x8 af[4], bf[4];
#pragma unroll
      for (int mt = 0; mt < 4; mt++) {
        int r = wm * 64 + mt * 16 + l16;
        af[mt] = *(const bf16x8*)&As[r * 64 + (((c * 4 + q) ^ (r & 7)) * 8)];
      }
#pragma unroll
      for (int nt = 0; nt < 4; nt++) {
        int r = wn * 64 + nt * 16 + l16;
        bf[nt] = *(const bf16x8*)&Bs[r * 64 + (((c * 4 + q) ^ (r & 7)) * 8)];
      }
#pragma unroll
      for (int mt = 0; mt < 4; mt++)
#pragma unroll
        for (int nt = 0; nt < 4; nt++)
          acc[mt][nt] = __builtin_amdgcn_mfma_f32_16x16x32_bf16(
              af[mt], bf[nt], acc[mt][nt], 0, 0, 0);
    }
    __syncthreads();
  }

  float fe_sum = 0.f;
#pragma unroll
  for (int mt = 0; mt < 4; mt++)
#pragma unroll
    for (int nt = 0; nt < 4; nt++) {
      const int gn = n0 + wn * 64 + nt * 16 + l16;
      const int gmb = m0 + wm * 64 + mt * 16 + q * 4;
      const float bvv = bvec[gn];
#pragma unroll
      for (int rg = 0; rg < 4; rg++) {
        const size_t idx = (size_t)(gmb + rg) * N + gn;
        float be = acc[mt][nt][rg] + bvv;
        float x1 = b2f(X1[idx]);
        float x2 = X2F32 ? ((const float*)X2)[idx]
                         : b2f(((const ushort_t*)X2)[idx]);
        fe_sum += be * (x1 - x2);
      }
    }
  float s = wave_reduce(fe_sum);
  if (lane == 0) atomicAdd(fe_acc, (double)s);
}

// ---------------- plain GEMM + f32-vector bias (Arnn pre-activation) ------------
__global__ __launch_bounds__(256)
void gemm_bias(const ushort_t* __restrict__ A, const ushort_t* __restrict__ BT,
               const float* __restrict__ biasv, float* __restrict__ Cf,
               int M, int N, int K) {
  __shared__ ushort_t As[128 * 64];
  __shared__ ushort_t Bs[128 * 64];
  const int tid = threadIdx.x;
  const int lane = tid & 63, wave = tid >> 6;
  const int wm = wave >> 1, wn = wave & 1;
  const int q = lane >> 4, l16 = lane & 15;
  int bx, by;
  xcd_swz(&bx, &by);
  const int m0 = by * 128, n0 = bx * 128;
  (void)lane;

  f32x4 acc[4][4];
#pragma unroll
  for (int i = 0; i < 4; i++)
#pragma unroll
    for (int j = 0; j < 4; j++) acc[i][j] = (f32x4){0.f, 0.f, 0.f, 0.f};

  for (int kk = 0; kk < K; kk += 64) {
#pragma unroll
    for (int j = 0; j < 4; j++) {
      int c = j * 256 + tid;
      int r = c >> 3, bg = (c & 7) ^ (r & 7);
      const int ldso = (j * 256 + wave * 64) * 8;
      GLOAD_LDS16(&A[(size_t)(m0 + r) * K + kk + bg * 8], &As[ldso]);
      GLOAD_LDS16(&BT[(size_t)(n0 + r) * K + kk + bg * 8], &Bs[ldso]);
    }
    __syncthreads();
#pragma unroll
    for (int c = 0; c < 2; c++) {
      bf16x8 af[4], bf[4];
#pragma unroll
      for (int mt = 0; mt < 4; mt++) {
        int r = wm * 64 + mt * 16 + l16;
        af[mt] = *(const bf16x8*)&As[r * 64 + (((c * 4 + q) ^ (r & 7)) * 8)];
      }
#pragma unroll
      for (int nt = 0; nt < 4; nt++) {
        int r = wn * 64 + nt * 16 + l16;
        bf[nt] = *(const bf16x8*)&Bs[r * 64 + (((c * 4 + q) ^ (r & 7)) * 8)];
      }
#pragma unroll
      for (int mt = 0; mt < 4; mt++)
#pragma unroll
        for (int nt = 0; nt < 4; nt++)
          acc[mt][nt] = __builtin_amdgcn_mfma_f32_16x16x32_bf16(
              af[mt], bf[nt], acc[mt][nt], 0, 0, 0);
    }
    __syncthreads();
  }

#pragma unroll
  for (int mt = 0; mt < 4; mt++)
#pragma unroll
    for (int nt = 0; nt < 4; nt++) {
      const int gn = n0 + wn * 64 + nt * 16 + l16;
      const int gmb = m0 + wm * 64 + mt * 16 + q * 4;
      const float bvv = biasv[gn];
#pragma unroll
      for (int rg = 0; rg < 4; rg++)
        Cf[(size_t)(gmb + rg) * N + gn] = acc[mt][nt][rg] + bvv;
    }
}

// ---------------- chunked RNN scan v5 (R8-proven: 256 blocks x 128 steps) -----
__global__ __launch_bounds__(1024, 1)
void rnn_scan(const float* __restrict__ Apre, const float* __restrict__ Wuu,
              ushort_t* __restrict__ shifted) {
  const int tid = threadIdx.x;
  const int j = tid >> 2;
  const int s = tid & 3;
  const int t_begin = blockIdx.x * 128;
  const int t_end = t_begin + 128;
  const int t0 = (t_begin >= 16) ? (t_begin - 16) : 0;

  float w[64];
#pragma unroll
  for (int i = 0; i < 64; i++) w[i] = Wuu[(size_t)(s * 64 + i) * 256 + j];

  __shared__ float u[2][280];
  __shared__ float asg[32 * 256];
  if (tid < 256) u[0][(tid >> 6) * 68 + (tid & 63)] = 0.f;
  if (blockIdx.x == 0 && s == 0) shifted[j] = 0;
  __syncthreads();

  const int jp = (j >> 6) * 68 + (j & 63);
  int p = 0;
  for (int tb = t0; tb < t_end; tb += 32) {
    int srow = tb + (tid >> 5);
    if (srow >= S_LEN) srow = S_LEN - 1;
    int scol = (tid & 31) * 8;
    float4 a0 = *(const float4*)&Apre[(size_t)srow * 256 + scol];
    float4 a1 = *(const float4*)&Apre[(size_t)srow * 256 + scol + 4];
    *(float4*)&asg[(tid >> 5) * 256 + scol] = a0;
    *(float4*)&asg[(tid >> 5) * 256 + scol + 4] = a1;
    __syncthreads();
#pragma unroll 1
    for (int i = 0; i < 32; i++) {
      const int t = tb + i;
      if (t >= t_end) break;
      float p0 = 0.f, p1 = 0.f, p2 = 0.f, p3 = 0.f;
#pragma unroll
      for (int qq = 0; qq < 64; qq += 4) {
        float4 uv = *(const float4*)&u[p][s * 68 + qq];
        p0 = fmaf(uv.x, w[qq + 0], p0);
        p1 = fmaf(uv.y, w[qq + 1], p1);
        p2 = fmaf(uv.z, w[qq + 2], p2);
        p3 = fmaf(uv.w, w[qq + 3], p3);
      }
      float ps = (p0 + p1) + (p2 + p3);
      ps += __shfl_xor(ps, 1, 64);
      ps += __shfl_xor(ps, 2, 64);
      float z = asg[i * 256 + j] + ps;
      float e = __expf(2.f * z);
      float unew = 1.f - 2.f * __builtin_amdgcn_rcpf(e + 1.f);
      if (s == 0) {
        u[1 - p][jp] = unew;
        if (t >= t_begin && (t + 1) < S_LEN)
          shifted[(size_t)(t + 1) * 256 + j] = f2b(unew);
      }
      __syncthreads();
      p ^= 1;
    }
  }
}

// ---------------- single prep kernel ----------------
__global__ __launch_bounds__(256)
void prep_all(const float* __restrict__ v_seq, ushort_t* __restrict__ vseq_bf,
              const float* __restrict__ Wyv, const float* __restrict__ Wyh1,
              const float* __restrict__ Wyh2, ushort_t* __restrict__ Wycat,
              const float* __restrict__ W1, ushort_t* __restrict__ BTw1t,
              ushort_t* __restrict__ BTw1,
              const float* __restrict__ W2, ushort_t* __restrict__ BTw2t,
              ushort_t* __restrict__ BTw2,
              const float* __restrict__ Wvu, ushort_t* __restrict__ BTwvu,
              const float* __restrict__ bv, const float* __restrict__ bh1,
              const float* __restrict__ bh2, float* __restrict__ bveccat) {
  int b = blockIdx.x;
  const int tid = threadIdx.x;
  if (b < 32768) { int i = b * 256 + tid; vseq_bf[i] = f2b(v_seq[i]); return; }
  b -= 32768;
  if (b < 256)  { int i = b * 256 + tid; Wycat[i] = f2b(Wyv[i]); return; }
  b -= 256;
  if (b < 512)  { int i = b * 256 + tid; Wycat[65536 + i] = f2b(Wyh1[i]); return; }
  b -= 512;
  if (b < 512)  { int i = b * 256 + tid; Wycat[196608 + i] = f2b(Wyh2[i]); return; }
  b -= 512;
  if (b < 512)  { int i = b * 256 + tid; BTw1t[i] = f2b(W1[i]); return; }
  b -= 512;
  if (b < 1024) { int i = b * 256 + tid; BTw2t[i] = f2b(W2[i]); return; }
  b -= 1024;
  if (b < 256)  { int i = b * 256 + tid; int r = i >> 8, c = i & 255;
                  BTwvu[c * 256 + r] = f2b(Wvu[i]); return; }
  b -= 256;
  if (b < 512)  { int i = b * 256 + tid; int r = i >> 9, c = i & 511;
                  BTw1[(size_t)c * 256 + r] = f2b(W1[i]); return; }
  b -= 512;
  if (b < 1024) { int i = b * 256 + tid; int r = i >> 9, c = i & 511;
                  BTw2[(size_t)c * 512 + r] = f2b(W2[i]); return; }
  b -= 1024;
  { int i = b * 256 + tid;
    if (i < 1280)
      bveccat[i] = (i < 256) ? bv[i] : (i < 768) ? bh1[i - 256] : bh2[i - 768]; }
}

__global__ void finalize_kernel(const double* __restrict__ acc, float* __restrict__ out) {
  out[0] = (float)(acc[0] / (double)S_LEN);
  out[1] = (float)(acc[1] / (double)S_LEN);
}

// ---------------- host orchestration ----------------
extern "C" void kernel_launch(void* const* d_in, const int* in_sizes, int n_in,
                              void* d_out, int out_size, void* d_ws, size_t ws_size,
                              hipStream_t stream) {
  (void)in_sizes; (void)n_in; (void)out_size; (void)ws_size;
  const float* v_seq = (const float*)d_in[0];
  const float* W1    = (const float*)d_in[1];
  const float* bv    = (const float*)d_in[2];
  const float* bh1   = (const float*)d_in[3];
  const float* W2    = (const float*)d_in[4];
  const float* bh2   = (const float*)d_in[5];
  const float* Wyv   = (const float*)d_in[6];
  const float* Wyh1  = (const float*)d_in[7];
  const float* Wyh2  = (const float*)d_in[8];
  const float* Wvu   = (const float*)d_in[9];
  const float* Wuu   = (const float*)d_in[10];
  const float* bu    = (const float*)d_in[11];
  float* out = (float*)d_out;

  const size_t SN = (size_t)S_LEN * NV;   // 8.4M
  const size_t SH = (size_t)S_LEN * NH;   // 16.8M
  char* base = (char*)d_ws;
  size_t cur = 0;
  auto take = [&](size_t bytes) { size_t o = cur; cur += (bytes + 255) & ~(size_t)255; return o; };
  double*   acc      = (double*)  (base + take(64));
  ushort_t* BTwvu    = (ushort_t*)(base + take(65536 * 2));
  ushort_t* Wycat    = (ushort_t*)(base + take((size_t)1280 * NR * 2));
  float*    bveccat  = (float*)   (base + take(1280 * 4));
  ushort_t* BTw1     = (ushort_t*)(base + take(131072 * 2));   // W1^T [512,256]
  ushort_t* BTw1t    = (ushort_t*)(base + take(131072 * 2));   // W1   [256,512]
  ushort_t* BTw2     = (ushort_t*)(base + take(262144 * 2));   // W2^T [512,512]
  ushort_t* BTw2t    = (ushort_t*)(base + take(262144 * 2));   // W2   [512,512]
  ushort_t* vseq_bf  = (ushort_t*)(base + take(SN * 2));
  ushort_t* shifted  = (ushort_t*)(base + take(SN * 2));
  float*    Arnn     = (float*)   (base + take(SN * 4));       // RNN pre-activation
  ushort_t* h1buf    = (ushort_t*)(base + take(SH * 2));       // h1 probs bf16
  ushort_t* sampA    = (ushort_t*)(base + take(SH * 2));       // RBM1 h samples
  ushort_t* sampB    = (ushort_t*)(base + take(SN * 2));       // RBM1 v samples
  ushort_t* sampC    = (ushort_t*)(base + take(SH * 2));       // RBM2 h2 samples
  ushort_t* sampD    = (ushort_t*)(base + take(SH * 2));       // RBM2 h1 samples

  uint32_t ka[20], kb[20];
  uint32_t K0 = 0u, K1 = 42u;
  for (int it = 0; it < 10; it++) {
    uint32_t n0, n1, a0, a1, b0, b1;
    tf2x32(K0, K1, 0u, 0u, &n0, &n1);
    tf2x32(K0, K1, 0u, 1u, &a0, &a1);
    tf2x32(K0, K1, 0u, 2u, &b0, &b1);
    ka[2 * it] = a0; kb[2 * it] = a1;
    ka[2 * it + 1] = b0; kb[2 * it + 1] = b1;
    K0 = n0; K1 = n1;
  }

  hipMemsetAsync(acc, 0, 2 * sizeof(double), stream);

  dim3 blk(256);
  prep_all<<<dim3(37381), blk, 0, stream>>>(
      v_seq, vseq_bf, Wyv, Wyh1, Wyh2, Wycat, W1, BTw1t, BTw1,
      W2, BTw2t, BTw2, Wvu, BTwvu, bv, bh1, bh2, bveccat);

  const int M = S_LEN;
  gemm_bias<<<dim3(2, M / 128), blk, 0, stream>>>(
      vseq_bf, BTwvu, bu, Arnn, M, NV, NV);
  rnn_scan<<<dim3(S_LEN / 128), dim3(1024), 0, stream>>>(Arnn, Wuu, shifted);

  const int OFF_BV = 0, OFF_BH1 = NV, OFF_BH2 = NV + NH;
  auto mk = [&](const ushort_t* A, const ushort_t* BT, int boff, ushort_t* C,
                ushort_t* C2, const float* vs, float sign, int key, int N, int K) {
    GemmArgs g;
    g.A = A; g.BT = BT;
    g.Ax = shifted;
    g.BXT = Wycat + (size_t)boff * 256;
    g.bvec = bveccat + boff;
    g.C = C; g.C2 = C2; g.vseqf = vs;
    g.fe_acc = acc; g.mon_acc = acc + 1; g.sign = sign;
    g.rk0 = key >= 0 ? ka[key] : 0; g.rk1 = key >= 0 ? kb[key] : 0;
    g.N = N; g.K = K; g.nbx = N / 128;
    return g;
  };

  // G1: sample h (sampA), h1 probs (h1buf), cost1 -= softplus(v_seq@W1+bh1t)
  gemm_samp<F_SAMP | F_H1 | F_FE>
      <<<dim3(4, M / 128), blk, 0, stream>>>(
      mk(vseq_bf, BTw1, OFF_BH1, sampA, h1buf, nullptr, 1.0f, 0, NH, NV));

  // 10 flattened pair dispatches: RBM1 chain + RBM2 chain
  GemmArgs V[5], Hh[4], A2g[5], B2g[5];
  for (int it = 0; it < 5; it++) {
    if (it > 0)
      Hh[it - 1] = mk(sampB, BTw1, OFF_BH1, sampA, nullptr, nullptr, 0.f,
                      2 * it, NH, NV);
    V[it] = mk(sampA, BTw1t, OFF_BV, sampB, nullptr,
               (it == 4) ? v_seq : nullptr, 0.f, 2 * it + 1, NV, NH);
    A2g[it] = mk((it == 0) ? h1buf : sampD,
                 BTw2, OFF_BH2, sampC, nullptr, nullptr,
                 (it == 0) ? 1.0f : 0.f, 10 + 2 * it, NH, NH);
    B2g[it] = mk(sampC, BTw2t, OFF_BH1, sampD, nullptr, nullptr, 0.f,
                 11 + 2 * it, NH, NH);
  }
  GemmArgs FE1 = mk(sampB, BTw1, OFF_BH1, nullptr, nullptr, nullptr, -1.0f,
                    -1, NH, NV);
  GemmArgs FE2 = mk(sampD, BTw2, OFF_BH2, nullptr, nullptr, nullptr, -1.0f,
                    -1, NH, NH);

  auto pgrid = [&](const GemmArgs& a, const GemmArgs& b) {
    return dim3(a.nbx + b.nbx, M / 128);
  };

  gemm_pair<F_SAMP, F_SAMP | F_FE>
      <<<pgrid(V[0], A2g[0]), blk, 0, stream>>>(V[0], A2g[0]);  // A2g[0]: A=h1buf
  gemm_pair<F_SAMP, F_SAMP>
      <<<pgrid(Hh[0], B2g[0]), blk, 0, stream>>>(Hh[0], B2g[0]);
  gemm_pair<F_SAMP, F_SAMP>
      <<<pgrid(V[1], A2g[1]), blk, 0, stream>>>(V[1], A2g[1]);
  gemm_pair<F_SAMP, F_SAMP>
      <<<pgrid(Hh[1], B2g[1]), blk, 0, stream>>>(Hh[1], B2g[1]);
  gemm_pair<F_SAMP, F_SAMP>
      <<<pgrid(V[2], A2g[2]), blk, 0, stream>>>(V[2], A2g[2]);
  gemm_pair<F_SAMP, F_SAMP>
      <<<pgrid(Hh[2], B2g[2]), blk, 0, stream>>>(Hh[2], B2g[2]);
  gemm_pair<F_SAMP, F_SAMP>
      <<<pgrid(V[3], A2g[3]), blk, 0, stream>>>(V[3], A2g[3]);
  gemm_pair<F_SAMP, F_SAMP>
      <<<pgrid(Hh[3], B2g[3]), blk, 0, stream>>>(Hh[3], B2g[3]);
  gemm_pair<F_SAMP | F_MON, F_SAMP>
      <<<pgrid(V[4], A2g[4]), blk, 0, stream>>>(V[4], A2g[4]);
  gemm_pair<F_FE, F_SAMP>
      <<<pgrid(FE1, B2g[4]), blk, 0, stream>>>(FE1, B2g[4]);

  // FE2(sample): cost2 += softplus(h1s@W2 + bh2t)
  gemm_samp<F_FE><<<dim3(4, M / 128), blk, 0, stream>>>(FE2);

  // Bias-dot terms (outside the hot GEMMs):
  // cost1 += sum (v_samp_final - v_seq) . bv_t      [X1=sampB, X2=v_seq f32]
  dot_bias<true><<<dim3(2, M / 128), blk, 0, stream>>>(
      shifted, Wycat + (size_t)OFF_BV * 256, bveccat + OFF_BV,
      sampB, v_seq, acc, NV);
  // cost2 += sum (h1_samp_final - h1) . bh1t        [X1=sampD, X2=h1buf bf16]
  dot_bias<false><<<dim3(4, M / 128), blk, 0, stream>>>(
      shifted, Wycat + (size_t)OFF_BH1 * 256, bveccat + OFF_BH1,
      sampD, h1buf, acc, NH);

  finalize_kernel<<<1, 1, 0, stream>>>(acc, out);
}